// Round 15
// baseline (217.199 us; speedup 1.0000x reference)
//
#include <hip/hip_runtime.h>
#include <hip/hip_bf16.h>
#include <stdint.h>

#define Rdim 1023
#define BFR  4190208           // 64*64*1023

typedef __bf16 bf16;
typedef __bf16 bf16x8 __attribute__((ext_vector_type(8)));
typedef __bf16 bf16x4 __attribute__((ext_vector_type(4)));
typedef float  f32x4  __attribute__((ext_vector_type(4)));
typedef float  f32x4u __attribute__((ext_vector_type(4), aligned(4)));

__device__ __forceinline__ void async16(const void* g, void* l) {
    __builtin_amdgcn_global_load_lds(
        (const __attribute__((address_space(1))) void*)g,
        (__attribute__((address_space(3))) void*)l, 16, 0, 0);
}

#define BAR()  do { __builtin_amdgcn_s_barrier(); __builtin_amdgcn_sched_barrier(0); } while(0)

// ---------------------------------------------------------------------------
// Prep (r10 verbatim — best known). 2-bit/64B-window swizzle for BK=32:
// chunk c of row m stored at (c&~3)|((c&3)^((m>>1)&3)).
// Measured (r13 probe): ~56.6 us, 87% of its 49 us traffic floor.
// ---------------------------------------------------------------------------
__global__ __launch_bounds__(256) void k_prep(
    const float* __restrict__ x,
    const float* __restrict__ w0, const float* __restrict__ w1,
    const float* __restrict__ w2, const float* __restrict__ w3,
    const float* __restrict__ Dl, const float* __restrict__ Dr,
    const float* __restrict__ El, const float* __restrict__ Er,
    bf16* __restrict__ args, bf16* __restrict__ dpad,
    float* __restrict__ out)
{
    const int blk = blockIdx.x;
    const int t   = threadIdx.x;

    if (blk < 4096) {
        const int b = blk >> 6;
        float wr0[16], wr1[16], wr2[16], wr3[16];
#pragma unroll
        for (int l = 0; l < 16; ++l) {
            wr0[l] = w0[b*16 + l]; wr1[l] = w1[b*16 + l];
            wr2[l] = w2[b*16 + l]; wr3[l] = w3[b*16 + l];
        }
        const float* xb = x + ((size_t)(b*16)*64 + (blk & 63)) * (size_t)Rdim;
        float a0[4] = {}, a1[4] = {}, a2[4] = {}, a3[4] = {};
        if (t < 255) {
#pragma unroll
            for (int l = 0; l < 16; ++l) {
                f32x4u v = *(const f32x4u*)(xb + (size_t)l*(64*(size_t)Rdim) + t*4);
#pragma unroll
                for (int j = 0; j < 4; ++j) {
                    a0[j] += wr0[l]*v[j]; a1[j] += wr1[l]*v[j];
                    a2[j] += wr2[l]*v[j]; a3[j] += wr3[l]*v[j];
                }
            }
        } else {
#pragma unroll
            for (int l = 0; l < 16; ++l) {
                const float* p = xb + (size_t)l*(64*(size_t)Rdim) + 1020;
#pragma unroll
                for (int j = 0; j < 3; ++j) {
                    float v = p[j];
                    a0[j] += wr0[l]*v; a1[j] += wr1[l]*v;
                    a2[j] += wr2[l]*v; a3[j] += wr3[l]*v;
                }
            }
        }
        const int c   = t >> 1;                       // 16B chunk = r/8
        const int S2  = (blk >> 1) & 3;               // 2-bit row swizzle
        const int cw  = (c & ~3) | ((c & 3) ^ S2);
        const int off = (cw << 3) + ((t & 1) << 2);
        bf16x4 s0, s1, s2, s3;
#pragma unroll
        for (int j = 0; j < 4; ++j) {
            s0[j] = (bf16)a0[j]; s1[j] = (bf16)a1[j];
            s2[j] = (bf16)a2[j]; s3[j] = (bf16)a3[j];
        }
        *(bf16x4*)(args +            (size_t)blk*1024 + off) = s0;
        *(bf16x4*)(args + 4194304 +  (size_t)blk*1024 + off) = s1;
        bf16* c12 = args + 8388608 + (size_t)blk*2048;
        *(bf16x4*)(c12 + off)        = s2;
        *(bf16x4*)(c12 + 1024 + off) = s3;
    } else if (blk < 6144) {
        const int id = (blk - 4096)*256 + t;
        const float* src; int n, c, K; size_t base;
        if (id < 262144) {
            const int m2  = id >> 17;
            src = m2 ? Dr : Dl;
            const int rem = id & 131071;
            n = rem >> 7; c = rem & 127; K = 1024;
            base = m2 ? 1048576u : 0u;
        } else {
            const int rem = id - 262144;
            n = rem >> 8; c = rem & 255; K = 2048;
            base = 2097152u;
            src = (c < 128) ? El : Er;
        }
        const int cl = c & 127;
        float v[8] = {};
        if (n < Rdim) {
            const float* sp = src + (size_t)n*Rdim + cl*8;
            if (cl < 127) {
                f32x4u u0 = *(const f32x4u*)sp;
                f32x4u u1 = *(const f32x4u*)(sp + 4);
#pragma unroll
                for (int j = 0; j < 4; ++j) { v[j] = u0[j]; v[4+j] = u1[j]; }
            } else {
                f32x4u u0 = *(const f32x4u*)sp;
#pragma unroll
                for (int j = 0; j < 4; ++j) v[j] = u0[j];
                v[4] = sp[4]; v[5] = sp[5]; v[6] = sp[6];
            }
        }
        const int swc = (c & ~3) | ((c & 3) ^ ((n >> 1) & 3));
        bf16x8 s;
#pragma unroll
        for (int j = 0; j < 8; ++j) s[j] = (bf16)v[j];
        *(bf16x8*)(dpad + base + (size_t)n*K + swc*8) = s;
    } else {
        const int k = t >> 6, b2 = t & 63;
        const float* w = (k==0) ? w0 : (k==1) ? w1 : (k==2) ? w2 : w3;
        float s = 0.f, mx = -1e30f;
#pragma unroll
        for (int l = 0; l < 16; ++l) {
            float p = w[b2*16 + l];
            s += p * logf(p + 1e-12f);
            mx = fmaxf(mx, p);
        }
        out[3*(size_t)BFR +       k*64 + b2] = -s / logf(16.f);
        out[3*(size_t)BFR + 256 + k*64 + b2] = mx;
    }
}

// ---------------------------------------------------------------------------
// GEMM — r10 verbatim structure, with a x4 REPEAT loop (PROBE: surfaces this
// dispatch above the ~157 us harness fills so rocprof top-5 shows MfmaUtil /
// VALUBusy / FETCH_SIZE / LDS conflicts for the GEMM). Idempotent: each rep
// re-zeros acc and rewrites identical outputs. Inter-rep safety: all LDS
// reads finish before each rep's last barrier; next prologue's vmcnt drains
// prior epilogue stores (oldest-first).
// ---------------------------------------------------------------------------
template<int BM, int NKT, int VM, bool CONS>
__device__ __forceinline__ void gemm_t(
    const bf16* __restrict__ Ab, const bf16* __restrict__ Bb,
    const float* __restrict__ rf, const float* __restrict__ rr,
    float* __restrict__ outp, char* lds, int mt, int nt)
{
    constexpr int AstB = CONS ? 4096 : 2048;
    constexpr int MI   = BM / 32;
    constexpr int ABUF = BM * 64;

    const int tid  = threadIdx.x;
    const int wave = tid >> 6, lane = tid & 63;
    const int wm   = wave >> 2, wn = wave & 3;
    const int lr   = lane & 15, lk = lane >> 4;
    const int cc16 = (lk ^ ((lr >> 1) & 3)) << 4;

    const char* AgT = (const char*)Ab + (size_t)(mt*BM  + (tid>>2))*AstB + (tid&3)*16;
    const char* BgT = (const char*)Bb + (size_t)(nt*256 + (tid>>2))*AstB + (tid&3)*16;

#define STG(bufidx, kt) do {                                                  \
    char* _a = lds + (bufidx)*ABUF + wave*1024;                               \
    char* _b = lds + 49152 + (bufidx)*16384 + wave*1024;                      \
    const size_t _ko = (size_t)(kt)*64;                                       \
    _Pragma("unroll") for (int i = 0; i < BM/128; ++i)                        \
        async16(AgT + (size_t)(i*128)*AstB + _ko, _a + i*8192);               \
    _Pragma("unroll") for (int i = 0; i < 2; ++i)                             \
        async16(BgT + (size_t)(i*128)*AstB + _ko, _b + i*8192);               \
} while(0)

#pragma unroll 1
    for (int rep = 0; rep < 4; ++rep) {
        f32x4 acc[MI][4] = {};
        bf16x8 af[MI], bfr[4];

        STG(0, 0); STG(1, 1);
        asm volatile("s_waitcnt vmcnt(%0)" :: "n"(VM) : "memory");
        BAR();

        int cb = 0;
        for (int kt = 0; kt < NKT; ++kt) {
            char* cA = lds + cb*ABUF;
            char* cB = lds + 49152 + cb*16384;
            int sb = cb + 2; if (sb >= 3) sb -= 3;
            const bool st = (kt + 2 < NKT);
#pragma unroll
            for (int mi = 0; mi < MI; ++mi)
                af[mi] = *(const bf16x8*)(cA + (wm*(BM/2) + mi*16 + lr)*64 + cc16);
#pragma unroll
            for (int j = 0; j < 4; ++j)
                bfr[j] = *(const bf16x8*)(cB + (wn*64 + j*16 + lr)*64 + cc16);
            if (st) STG(sb, kt+2);
            __builtin_amdgcn_s_setprio(1);
#pragma unroll
            for (int mi = 0; mi < MI; ++mi)
#pragma unroll
            for (int j = 0; j < 4; ++j)
                acc[mi][j] = __builtin_amdgcn_mfma_f32_16x16x32_bf16(
                    af[mi], bfr[j], acc[mi][j], 0, 0, 0);
            __builtin_amdgcn_s_setprio(0);
            if (st)                { asm volatile("s_waitcnt vmcnt(%0)" :: "n"(VM) : "memory"); }
            else if (kt == NKT-2)  { asm volatile("s_waitcnt vmcnt(0)" ::: "memory"); }
            BAR();
            cb = cb + 1; if (cb == 3) cb = 0;
        }

#pragma unroll
        for (int mi = 0; mi < MI; ++mi) {
            const int gm0 = mt*BM + wm*(BM/2) + mi*16 + lk*4;
#pragma unroll
            for (int j = 0; j < 4; ++j) {
                const int gn = nt*256 + wn*64 + j*16 + lr;
                if (gn < Rdim) {
                    const float rv = CONS ? rr[gn] : 0.f;
#pragma unroll
                    for (int q = 0; q < 4; ++q) {
                        float v = acc[mi][j][q];
                        if (CONS) v += rf[gm0 + q] * rv;
                        outp[(size_t)(gm0 + q)*Rdim + gn] = v;
                    }
                }
            }
        }
    }
#undef STG
}

__global__ __launch_bounds__(512, 1) void k_gemm(
    const bf16* __restrict__ args, const bf16* __restrict__ dpad,
    const float* __restrict__ root_filler, const float* __restrict__ root_role,
    float* __restrict__ out)
{
    __shared__ char lds[98304];
    const int bid = blockIdx.x;
    const int xcd = bid & 7, idx = bid >> 3;

    if (idx < 16) {
        const int tile = xcd*16 + idx;
        gemm_t<128, 64, 3, true >(args + 8388608, dpad + 2097152,
            root_filler, root_role, out + 2*(size_t)BFR, lds, tile >> 2, tile & 3);
    } else if (idx < 24) {
        const int tile = xcd*8 + idx - 16;
        gemm_t<256, 32, 4, false>(args, dpad,
            root_filler, root_role, out, lds, tile >> 2, tile & 3);
    } else {
        const int tile = xcd*8 + idx - 24;
        gemm_t<256, 32, 4, false>(args + 4194304, dpad + 1048576,
            root_filler, root_role, out + (size_t)BFR, lds, tile >> 2, tile & 3);
    }
}

// ---------------------------------------------------------------------------
// PROBE ROUND: GEMM repeated x4 inside its dispatch (idempotent) so its
// rocprof counters surface in top-5. Baseline config otherwise = r10 best.
// ---------------------------------------------------------------------------
extern "C" void kernel_launch(void* const* d_in, const int* in_sizes, int n_in,
                              void* d_out, int out_size, void* d_ws, size_t ws_size,
                              hipStream_t stream)
{
    const float* x           = (const float*)d_in[0];
    const float* car_w       = (const float*)d_in[1];
    const float* cdr_w       = (const float*)d_in[2];
    const float* cons1_w     = (const float*)d_in[3];
    const float* cons2_w     = (const float*)d_in[4];
    const float* root_filler = (const float*)d_in[5];
    const float* Dl          = (const float*)d_in[6];
    const float* Dr          = (const float*)d_in[7];
    const float* El          = (const float*)d_in[8];
    const float* Er          = (const float*)d_in[9];
    const float* root_role   = (const float*)d_in[10];
    float* out = (float*)d_out;

    bf16* args = (bf16*)d_ws;                 // 33.5 MB
    bf16* dpad = args + 16777216;             //  8.4 MB

    k_prep<<<dim3(6145), dim3(256), 0, stream>>>(
        x, car_w, cdr_w, cons1_w, cons2_w, Dl, Dr, El, Er, args, dpad, out);
    k_gemm<<<dim3(256),  dim3(512), 0, stream>>>(
        args, dpad, root_filler, root_role, out);
}

// Round 16
// 110.279 us; speedup vs baseline: 1.9695x; 1.9695x over previous
//
#include <hip/hip_runtime.h>
#include <hip/hip_bf16.h>
#include <stdint.h>

#define Rdim 1023
#define BFR  4190208           // 64*64*1023

typedef __bf16 bf16;
typedef __bf16 bf16x8 __attribute__((ext_vector_type(8)));
typedef __bf16 bf16x4 __attribute__((ext_vector_type(4)));
typedef float  f32x4  __attribute__((ext_vector_type(4)));
typedef float  f32x4u __attribute__((ext_vector_type(4), aligned(4)));

__device__ __forceinline__ void async16(const void* g, void* l) {
    __builtin_amdgcn_global_load_lds(
        (const __attribute__((address_space(1))) void*)g,
        (__attribute__((address_space(3))) void*)l, 16, 0, 0);
}

#define BAR()  do { __builtin_amdgcn_s_barrier(); __builtin_amdgcn_sched_barrier(0); } while(0)

// ---------------------------------------------------------------------------
// Prep (r10 verbatim — frozen; measured 56.6 us, 87% of its 49 us floor).
// 2-bit/64B-window swizzle: chunk c of row m stored at (c&~3)|((c&3)^((m>>1)&3)).
// ---------------------------------------------------------------------------
__global__ __launch_bounds__(256) void k_prep(
    const float* __restrict__ x,
    const float* __restrict__ w0, const float* __restrict__ w1,
    const float* __restrict__ w2, const float* __restrict__ w3,
    const float* __restrict__ Dl, const float* __restrict__ Dr,
    const float* __restrict__ El, const float* __restrict__ Er,
    bf16* __restrict__ args, bf16* __restrict__ dpad,
    float* __restrict__ out)
{
    const int blk = blockIdx.x;
    const int t   = threadIdx.x;

    if (blk < 4096) {
        const int b = blk >> 6;
        float wr0[16], wr1[16], wr2[16], wr3[16];
#pragma unroll
        for (int l = 0; l < 16; ++l) {
            wr0[l] = w0[b*16 + l]; wr1[l] = w1[b*16 + l];
            wr2[l] = w2[b*16 + l]; wr3[l] = w3[b*16 + l];
        }
        const float* xb = x + ((size_t)(b*16)*64 + (blk & 63)) * (size_t)Rdim;
        float a0[4] = {}, a1[4] = {}, a2[4] = {}, a3[4] = {};
        if (t < 255) {
#pragma unroll
            for (int l = 0; l < 16; ++l) {
                f32x4u v = *(const f32x4u*)(xb + (size_t)l*(64*(size_t)Rdim) + t*4);
#pragma unroll
                for (int j = 0; j < 4; ++j) {
                    a0[j] += wr0[l]*v[j]; a1[j] += wr1[l]*v[j];
                    a2[j] += wr2[l]*v[j]; a3[j] += wr3[l]*v[j];
                }
            }
        } else {
#pragma unroll
            for (int l = 0; l < 16; ++l) {
                const float* p = xb + (size_t)l*(64*(size_t)Rdim) + 1020;
#pragma unroll
                for (int j = 0; j < 3; ++j) {
                    float v = p[j];
                    a0[j] += wr0[l]*v; a1[j] += wr1[l]*v;
                    a2[j] += wr2[l]*v; a3[j] += wr3[l]*v;
                }
            }
        }
        const int c   = t >> 1;                       // 16B chunk = r/8
        const int S2  = (blk >> 1) & 3;               // 2-bit row swizzle
        const int cw  = (c & ~3) | ((c & 3) ^ S2);
        const int off = (cw << 3) + ((t & 1) << 2);
        bf16x4 s0, s1, s2, s3;
#pragma unroll
        for (int j = 0; j < 4; ++j) {
            s0[j] = (bf16)a0[j]; s1[j] = (bf16)a1[j];
            s2[j] = (bf16)a2[j]; s3[j] = (bf16)a3[j];
        }
        *(bf16x4*)(args +            (size_t)blk*1024 + off) = s0;
        *(bf16x4*)(args + 4194304 +  (size_t)blk*1024 + off) = s1;
        bf16* c12 = args + 8388608 + (size_t)blk*2048;
        *(bf16x4*)(c12 + off)        = s2;
        *(bf16x4*)(c12 + 1024 + off) = s3;
    } else if (blk < 6144) {
        const int id = (blk - 4096)*256 + t;
        const float* src; int n, c, K; size_t base;
        if (id < 262144) {
            const int m2  = id >> 17;
            src = m2 ? Dr : Dl;
            const int rem = id & 131071;
            n = rem >> 7; c = rem & 127; K = 1024;
            base = m2 ? 1048576u : 0u;
        } else {
            const int rem = id - 262144;
            n = rem >> 8; c = rem & 255; K = 2048;
            base = 2097152u;
            src = (c < 128) ? El : Er;
        }
        const int cl = c & 127;
        float v[8] = {};
        if (n < Rdim) {
            const float* sp = src + (size_t)n*Rdim + cl*8;
            if (cl < 127) {
                f32x4u u0 = *(const f32x4u*)sp;
                f32x4u u1 = *(const f32x4u*)(sp + 4);
#pragma unroll
                for (int j = 0; j < 4; ++j) { v[j] = u0[j]; v[4+j] = u1[j]; }
            } else {
                f32x4u u0 = *(const f32x4u*)sp;
#pragma unroll
                for (int j = 0; j < 4; ++j) v[j] = u0[j];
                v[4] = sp[4]; v[5] = sp[5]; v[6] = sp[6];
            }
        }
        const int swc = (c & ~3) | ((c & 3) ^ ((n >> 1) & 3));
        bf16x8 s;
#pragma unroll
        for (int j = 0; j < 8; ++j) s[j] = (bf16)v[j];
        *(bf16x8*)(dpad + base + (size_t)n*K + swc*8) = s;
    } else {
        const int k = t >> 6, b2 = t & 63;
        const float* w = (k==0) ? w0 : (k==1) ? w1 : (k==2) ? w2 : w3;
        float s = 0.f, mx = -1e30f;
#pragma unroll
        for (int l = 0; l < 16; ++l) {
            float p = w[b2*16 + l];
            s += p * logf(p + 1e-12f);
            mx = fmaxf(mx, p);
        }
        out[3*(size_t)BFR +       k*64 + b2] = -s / logf(16.f);
        out[3*(size_t)BFR + 256 + k*64 + b2] = mx;
    }
}

// ---------------------------------------------------------------------------
// GEMM — 2 blocks/CU at matched per-wave intensity (the r15-probe fix:
// MfmaUtil was 36% with 47% wait states at 1 block/CU; co-resident block
// hides the per-kt vmcnt+barrier convoy). BN=128 split: car/cdr 256x128
// (K=1024), cons 128x128 (K=2048) -> 512 uniform blocks = 2/CU.
// 8 waves 4M x 2N (wave = BM/4 x 64): car 16 MFMA + 8 ds_read/kt/wave.
// Triple-buffered LDS 72 KiB (A 3xBM*64 @0, B 3x8KB @49152), 1-barrier
// loop, counted vmcnt(U), U = BM/128+1 async16/kt. Same XOR swizzle
// (0 conflicts measured), same epilogue.
// ---------------------------------------------------------------------------
template<int BM, int NKT, bool CONS>
__device__ __forceinline__ void gemm_t(
    const bf16* __restrict__ Ab, const bf16* __restrict__ Bb,
    const float* __restrict__ rf, const float* __restrict__ rr,
    float* __restrict__ outp, char* lds, int mt, int nt)
{
    constexpr int AstB = CONS ? 4096 : 2048;   // row stride bytes (A and B)
    constexpr int MI   = BM / 64;              // A frags per wave
    constexpr int ABUF = BM * 64;              // bytes per A buffer
    constexpr int U    = BM/128 + 1;           // async16 units per K-tile

    const int tid  = threadIdx.x;
    const int wave = tid >> 6, lane = tid & 63;
    const int wm   = wave >> 1, wn = wave & 1; // 4M x 2N
    const int lr   = lane & 15, lk = lane >> 4;
    const int cc16 = (lk ^ ((lr >> 1) & 3)) << 4;

    const char* AgT = (const char*)Ab + (size_t)(mt*BM  + (tid>>2))*AstB + (tid&3)*16;
    const char* BgT = (const char*)Bb + (size_t)(nt*128 + (tid>>2))*AstB + (tid&3)*16;

    f32x4 acc[MI][4] = {};
    bf16x8 af[MI], bfr[4];

#define STG(bufidx, kt) do {                                                  \
    char* _a = lds + (bufidx)*ABUF + wave*1024;                               \
    char* _b = lds + 49152 + (bufidx)*8192 + wave*1024;                       \
    const size_t _ko = (size_t)(kt)*64;                                       \
    _Pragma("unroll") for (int i = 0; i < BM/128; ++i)                        \
        async16(AgT + (size_t)(i*128)*AstB + _ko, _a + i*8192);               \
    async16(BgT + _ko, _b);                                                   \
} while(0)

    // prologue: kt0 -> buf0, kt1 -> buf1; wait kt0 landed (kt1's U remain)
    STG(0, 0); STG(1, 1);
    asm volatile("s_waitcnt vmcnt(%0)" :: "n"(U) : "memory");
    BAR();

    int cb = 0;
    for (int kt = 0; kt < NKT; ++kt) {
        char* cA = lds + cb*ABUF;
        char* cB = lds + 49152 + cb*8192;
        int sb = cb + 2; if (sb >= 3) sb -= 3;
        const bool st = (kt + 2 < NKT);
#pragma unroll
        for (int mi = 0; mi < MI; ++mi)
            af[mi] = *(const bf16x8*)(cA + (wm*(BM/4) + mi*16 + lr)*64 + cc16);
#pragma unroll
        for (int j = 0; j < 4; ++j)
            bfr[j] = *(const bf16x8*)(cB + (wn*64 + j*16 + lr)*64 + cc16);
        if (st) STG(sb, kt+2);
        __builtin_amdgcn_s_setprio(1);
#pragma unroll
        for (int mi = 0; mi < MI; ++mi)
#pragma unroll
        for (int j = 0; j < 4; ++j)
            acc[mi][j] = __builtin_amdgcn_mfma_f32_16x16x32_bf16(
                af[mi], bfr[j], acc[mi][j], 0, 0, 0);
        __builtin_amdgcn_s_setprio(0);
        if (st)                { asm volatile("s_waitcnt vmcnt(%0)" :: "n"(U) : "memory"); }
        else if (kt == NKT-2)  { asm volatile("s_waitcnt vmcnt(0)" ::: "memory"); }
        BAR();
        cb = cb + 1; if (cb == 3) cb = 0;
    }
#undef STG

    // epilogue: 16x16 C/D: col = lane&15, row = (lane>>4)*4 + q
#pragma unroll
    for (int mi = 0; mi < MI; ++mi) {
        const int gm0 = mt*BM + wm*(BM/4) + mi*16 + lk*4;
#pragma unroll
        for (int j = 0; j < 4; ++j) {
            const int gn = nt*128 + wn*64 + j*16 + lr;
            if (gn < Rdim) {
                const float rv = CONS ? rr[gn] : 0.f;
#pragma unroll
                for (int q = 0; q < 4; ++q) {
                    float v = acc[mi][j][q];
                    if (CONS) v += rf[gm0 + q] * rv;
                    outp[(size_t)(gm0 + q)*Rdim + gn] = v;
                }
            }
        }
    }
}

// 512 blocks, 2/CU: per XCD 32 cons (128x128, K=2048, FIRST) + 16 car +
// 16 cdr (256x128, K=1024) — uniform FLOPs per block.
__global__ __launch_bounds__(512, 4) void k_gemm(
    const bf16* __restrict__ args, const bf16* __restrict__ dpad,
    const float* __restrict__ root_filler, const float* __restrict__ root_role,
    float* __restrict__ out)
{
    __shared__ char lds[73728];       // 72 KiB -> 2 blocks/CU
    const int bid = blockIdx.x;
    const int xcd = bid & 7, idx = bid >> 3;   // idx 0..63

    if (idx < 32) {
        const int tile = xcd*32 + idx;         // 0..255: mt 0..31, nt 0..7
        gemm_t<128, 64, true >(args + 8388608, dpad + 2097152,
            root_filler, root_role, out + 2*(size_t)BFR, lds, tile >> 3, tile & 7);
    } else if (idx < 48) {
        const int tile = xcd*16 + idx - 32;    // 0..127: mt 0..15, nt 0..7
        gemm_t<256, 32, false>(args, dpad,
            root_filler, root_role, out, lds, tile >> 3, tile & 7);
    } else {
        const int tile = xcd*16 + idx - 48;
        gemm_t<256, 32, false>(args + 4194304, dpad + 1048576,
            root_filler, root_role, out + (size_t)BFR, lds, tile >> 3, tile & 7);
    }
}

// ---------------------------------------------------------------------------
extern "C" void kernel_launch(void* const* d_in, const int* in_sizes, int n_in,
                              void* d_out, int out_size, void* d_ws, size_t ws_size,
                              hipStream_t stream)
{
    const float* x           = (const float*)d_in[0];
    const float* car_w       = (const float*)d_in[1];
    const float* cdr_w       = (const float*)d_in[2];
    const float* cons1_w     = (const float*)d_in[3];
    const float* cons2_w     = (const float*)d_in[4];
    const float* root_filler = (const float*)d_in[5];
    const float* Dl          = (const float*)d_in[6];
    const float* Dr          = (const float*)d_in[7];
    const float* El          = (const float*)d_in[8];
    const float* Er          = (const float*)d_in[9];
    const float* root_role   = (const float*)d_in[10];
    float* out = (float*)d_out;

    bf16* args = (bf16*)d_ws;                 // 33.5 MB
    bf16* dpad = args + 16777216;             //  8.4 MB

    k_prep<<<dim3(6145), dim3(256), 0, stream>>>(
        x, car_w, cdr_w, cons1_w, cons2_w, Dl, Dr, El, Er, args, dpad, out);
    k_gemm<<<dim3(512),  dim3(512), 0, stream>>>(
        args, dpad, root_filler, root_role, out);
}